// Round 1
// baseline (986.000 us; speedup 1.0000x reference)
//
#include <hip/hip_runtime.h>
#include <hip/hip_bf16.h>

#define IN_DIM 1024
#define H_DIM  1024
#define C_DIM  16
#define B_DIM  4096
#define K_DIM  2048      // IN + H
#define N_DIM  32768     // C * 2H
#define M_DIM  4096      // B

typedef __attribute__((ext_vector_type(8))) short short8;
typedef __attribute__((ext_vector_type(4))) float f32x4;

__device__ __forceinline__ unsigned short f2bf_rne(float f) {
  union { float f; unsigned u; } a; a.f = f;
  unsigned r = a.u + 0x7FFFu + ((a.u >> 16) & 1u);
  return (unsigned short)(r >> 16);
}

// Pack rows: out[r][0:1024] = bf16(xs[r][:]), out[r][1024:2048] = bf16(hs[r][:])
__global__ void convert_pack_kernel(const float* __restrict__ xs,
                                    const float* __restrict__ hs,
                                    unsigned short* __restrict__ out,
                                    int rows) {
  long total = (long)rows * (K_DIM / 8);
  for (long i = blockIdx.x * (long)blockDim.x + threadIdx.x; i < total;
       i += (long)gridDim.x * blockDim.x) {
    long e = i * 8;
    int r = (int)(e >> 11);
    int k = (int)(e & 2047);
    const float* src = (k < IN_DIM) ? (xs + (long)r * IN_DIM + k)
                                    : (hs + (long)r * H_DIM + (k - IN_DIM));
    float4 v0 = *(const float4*)(src);
    float4 v1 = *(const float4*)(src + 4);
    union { unsigned short u[8]; short8 s; } p;
    p.u[0] = f2bf_rne(v0.x); p.u[1] = f2bf_rne(v0.y);
    p.u[2] = f2bf_rne(v0.z); p.u[3] = f2bf_rne(v0.w);
    p.u[4] = f2bf_rne(v1.x); p.u[5] = f2bf_rne(v1.y);
    p.u[6] = f2bf_rne(v1.z); p.u[7] = f2bf_rne(v1.w);
    *(short8*)(out + e) = p.s;
  }
}

__device__ __forceinline__ void gload_lds16(const void* g, void* l) {
  __builtin_amdgcn_global_load_lds(
      (const __attribute__((address_space(1))) unsigned int*)g,
      (__attribute__((address_space(3))) unsigned int*)l, 16, 0, 0);
}

// C = A(M x K) * Bt(N x K)^T + bias, fused sigmoid/tanh epilogue.
// 128x128 tile, BK=32, 4 waves (2x2), each wave 64x64 = 4x4 16x16 frags.
__global__ void __launch_bounds__(256)
gemm_act_kernel(const short* __restrict__ A,   // [M][K] bf16 bits
                const short* __restrict__ Bt,  // [N][K] bf16 bits
                const float* __restrict__ bias,// [N]
                float* __restrict__ out) {
  __shared__ short lA[128 * 32];
  __shared__ short lB[128 * 32];

  // bijective XCD swizzle (nwg = 8192, divisible by 8)
  int nwg = gridDim.x;
  int cpx = nwg >> 3;
  int wg  = (blockIdx.x & 7) * cpx + (blockIdx.x >> 3);
  int mt = wg & 31;          // M/128 = 32 tiles (fast dim: share B panel)
  int nt = wg >> 5;          // N/128 = 256 tiles
  int m0 = mt * 128;
  int n0 = nt * 128;

  int tid  = threadIdx.x;
  int lane = tid & 63;
  int wid  = tid >> 6;
  int wm = (wid >> 1) * 64;  // wave row offset in tile
  int wn = (wid & 1) * 64;   // wave col offset in tile

  f32x4 acc[4][4] = {};

  // staging: thread t stages 16B at lds elem t*8 (+2048 for 2nd round)
  const int e0   = tid * 8;
  const int row0 = e0 >> 5;       // /32 elems per lds row
  const int kk0  = e0 & 31;
  const short* Ab = A  + (long)(m0 + row0) * K_DIM + kk0;
  const short* Bb = Bt + (long)(n0 + row0) * K_DIM + kk0;

  const int fr = lane & 15;        // fragment row
  const int fk = (lane >> 4) * 8;  // fragment k offset

  for (int kt = 0; kt < K_DIM / 32; ++kt) {
    const int ko = kt * 32;
    gload_lds16(Ab + ko,               lA + e0);
    gload_lds16(Ab + 64 * K_DIM + ko,  lA + e0 + 2048);
    gload_lds16(Bb + ko,               lB + e0);
    gload_lds16(Bb + 64 * K_DIM + ko,  lB + e0 + 2048);
    __syncthreads();   // drains vmcnt before use

    short8 a[4], b[4];
#pragma unroll
    for (int i = 0; i < 4; ++i)
      a[i] = *(const short8*)(lA + (wm + i * 16 + fr) * 32 + fk);
#pragma unroll
    for (int i = 0; i < 4; ++i)
      b[i] = *(const short8*)(lB + (wn + i * 16 + fr) * 32 + fk);
#pragma unroll
    for (int i = 0; i < 4; ++i)
#pragma unroll
      for (int j = 0; j < 4; ++j)
        acc[i][j] = __builtin_amdgcn_mfma_f32_16x16x32_bf16(a[i], b[j], acc[i][j], 0, 0, 0);
    __syncthreads();   // before next-tile overwrite
  }

  // epilogue: C/D layout col=lane&15, row=(lane>>4)*4+j
  const int crow = (lane >> 4) * 4;
  const int ccol = lane & 15;
  const long HALF = (long)B_DIM * C_DIM * H_DIM;  // 67108864
#pragma unroll
  for (int i = 0; i < 4; ++i) {
    int gb0 = m0 + wm + i * 16 + crow;
#pragma unroll
    for (int jj = 0; jj < 4; ++jj) {
      int gn = n0 + wn + jj * 16 + ccol;
      float bia = bias[gn];
      int c = gn >> 11;
      int o = gn & 2047;
#pragma unroll
      for (int j = 0; j < 4; ++j) {
        float v = acc[i][jj][j] + bia;
        long b = gb0 + j;
        if (o < H_DIM) {  // input_gate = sigmoid -> output 1 (second half)
          float r = 1.0f / (1.0f + __expf(-v));
          out[HALF + (b * C_DIM + c) * H_DIM + o] = r;
        } else {          // cell_input = tanh -> output 0 (first half)
          float av = fabsf(v);
          float t = __expf(-2.0f * av);
          float r = (1.0f - t) / (1.0f + t);
          out[(b * C_DIM + c) * H_DIM + (o - H_DIM)] = (v < 0.0f) ? -r : r;
        }
      }
    }
  }
}

// Correctness-only fallback if workspace is too small for bf16 staging.
__global__ void fallback_kernel(const float* __restrict__ x,
                                const float* __restrict__ h,
                                const float* __restrict__ Wx,
                                const float* __restrict__ bx,
                                const float* __restrict__ Wh,
                                float* __restrict__ out) {
  int b = blockIdx.x;
  int c = blockIdx.y;
  __shared__ float lx[IN_DIM], lh[H_DIM];
  for (int i = threadIdx.x; i < IN_DIM; i += blockDim.x) {
    lx[i] = x[(long)b * IN_DIM + i];
    lh[i] = h[(long)b * H_DIM + i];
  }
  __syncthreads();
  const long HALF = (long)B_DIM * C_DIM * H_DIM;
  for (int o = threadIdx.x; o < 2 * H_DIM; o += blockDim.x) {
    const float* wx = Wx + ((long)c * 2 * H_DIM + o) * IN_DIM;
    const float* wh = Wh + ((long)c * 2 * H_DIM + o) * H_DIM;
    float acc = bx[c * 2 * H_DIM + o];
    for (int k = 0; k < IN_DIM; ++k) acc += lx[k] * wx[k];
    for (int k = 0; k < H_DIM; ++k) acc += lh[k] * wh[k];
    if (o < H_DIM) {
      out[HALF + ((long)b * C_DIM + c) * H_DIM + o] = 1.0f / (1.0f + __expf(-acc));
    } else {
      float av = fabsf(acc);
      float t = __expf(-2.0f * av);
      float r = (1.0f - t) / (1.0f + t);
      out[((long)b * C_DIM + c) * H_DIM + (o - H_DIM)] = (acc < 0.0f) ? -r : r;
    }
  }
}

extern "C" void kernel_launch(void* const* d_in, const int* in_sizes, int n_in,
                              void* d_out, int out_size, void* d_ws, size_t ws_size,
                              hipStream_t stream) {
  const float* x  = (const float*)d_in[0];   // (B, IN)
  const float* h  = (const float*)d_in[1];   // (B, H)
  const float* Wx = (const float*)d_in[2];   // (C, 2H, IN)
  const float* bx = (const float*)d_in[3];   // (C, 2H)
  const float* Wh = (const float*)d_in[4];   // (C, 2H, H)
  float* out = (float*)d_out;                // [cell_input | input_gate], each (B,C,H)

  const size_t needA = (size_t)M_DIM * K_DIM * sizeof(short);  // 16 MiB
  const size_t needB = (size_t)N_DIM * K_DIM * sizeof(short);  // 128 MiB
  if (ws_size < needA + needB) {
    dim3 g(B_DIM, C_DIM);
    fallback_kernel<<<g, 256, 0, stream>>>(x, h, Wx, bx, Wh, out);
    return;
  }

  unsigned short* Abf = (unsigned short*)d_ws;
  unsigned short* Bbf = (unsigned short*)((char*)d_ws + needA);

  convert_pack_kernel<<<2048, 256, 0, stream>>>(x, h, Abf, M_DIM);
  convert_pack_kernel<<<4096, 256, 0, stream>>>(Wx, Wh, Bbf, N_DIM);

  gemm_act_kernel<<<8192, 256, 0, stream>>>((const short*)Abf, (const short*)Bbf,
                                            bx, out);
}

// Round 2
// 826.745 us; speedup vs baseline: 1.1926x; 1.1926x over previous
//
#include <hip/hip_runtime.h>
#include <hip/hip_bf16.h>

#define IN_DIM 1024
#define H_DIM  1024
#define C_DIM  16
#define B_DIM  4096
#define K_DIM  2048      // IN + H
#define N_DIM  32768     // C * 2H
#define M_DIM  4096      // B
#define NKT    64        // K_DIM / 32 K-tiles

typedef __attribute__((ext_vector_type(8))) short short8;
typedef __attribute__((ext_vector_type(4))) float f32x4;

__device__ __forceinline__ unsigned short f2bf_rne(float f) {
  union { float f; unsigned u; } a; a.f = f;
  unsigned r = a.u + 0x7FFFu + ((a.u >> 16) & 1u);
  return (unsigned short)(r >> 16);
}

// Pack rows: out[r][0:1024] = bf16(xs[r][:]), out[r][1024:2048] = bf16(hs[r][:])
__global__ void convert_pack_kernel(const float* __restrict__ xs,
                                    const float* __restrict__ hs,
                                    unsigned short* __restrict__ out,
                                    int rows) {
  long total = (long)rows * (K_DIM / 8);
  for (long i = blockIdx.x * (long)blockDim.x + threadIdx.x; i < total;
       i += (long)gridDim.x * blockDim.x) {
    long e = i * 8;
    int r = (int)(e >> 11);
    int k = (int)(e & 2047);
    const float* src = (k < IN_DIM) ? (xs + (long)r * IN_DIM + k)
                                    : (hs + (long)r * H_DIM + (k - IN_DIM));
    float4 v0 = *(const float4*)(src);
    float4 v1 = *(const float4*)(src + 4);
    union { unsigned short u[8]; short8 s; } p;
    p.u[0] = f2bf_rne(v0.x); p.u[1] = f2bf_rne(v0.y);
    p.u[2] = f2bf_rne(v0.z); p.u[3] = f2bf_rne(v0.w);
    p.u[4] = f2bf_rne(v1.x); p.u[5] = f2bf_rne(v1.y);
    p.u[6] = f2bf_rne(v1.z); p.u[7] = f2bf_rne(v1.w);
    *(short8*)(out + e) = p.s;
  }
}

__device__ __forceinline__ void gload_lds16(const void* g, void* l) {
  __builtin_amdgcn_global_load_lds(
      (const __attribute__((address_space(1))) unsigned int*)g,
      (__attribute__((address_space(3))) unsigned int*)l, 16, 0, 0);
}

// C = A(M x K) * Bt(N x K)^T + bias, fused sigmoid/tanh epilogue.
// 256x256 tile, BK=32, 8 waves (2Mx4N), per-wave 128x64 output.
// 3 LDS buffers, counted vmcnt(4) pipeline (prefetch distance 2 K-tiles),
// T2 chunk-XOR swizzle, T5 setprio, 2 phases per K-tile.
__global__ void __launch_bounds__(512, 2)
gemm_act_kernel(const short* __restrict__ A,   // [M][K] bf16 bits
                const short* __restrict__ Bt,  // [N][K] bf16 bits
                const float* __restrict__ bias,// [N]
                float* __restrict__ out) {
  extern __shared__ short lds[];
  short* sA0 = lds;          short* sB0 = lds + 24576;
  short* sA1 = lds + 8192;   short* sB1 = lds + 32768;
  short* sA2 = lds + 16384;  short* sB2 = lds + 40960;

  // bijective XCD swizzle (nwg = 2048, divisible by 8); m-fastest tiling
  int cpx = (int)gridDim.x >> 3;
  int wg  = ((int)blockIdx.x & 7) * cpx + ((int)blockIdx.x >> 3);
  int mt = wg & 15;           // M/256 = 16 tiles
  int nt = wg >> 4;           // N/256 = 128 tiles
  int m0 = mt * 256;
  int n0 = nt * 256;

  const int tid  = (int)threadIdx.x;
  const int lane = tid & 63;
  const int wid  = tid >> 6;
  const int wr   = wid >> 2;   // 0..1 -> wave rows offset wr*128
  const int wc   = wid & 3;    // 0..3 -> wave cols offset wc*64

  // ---- staging addresses (T2 pre-swizzled global source, linear LDS dest) --
  const int srow = tid >> 2;                       // 0..127
  const int schk = (tid & 3) ^ ((tid >> 3) & 3);   // swizzled 16B chunk
  const long gA0 = (long)(m0 + srow) * K_DIM + schk * 8;
  const long gB0 = (long)(n0 + srow) * K_DIM + schk * 8;
  const int  lo0 = tid * 8;
  const int  lo1 = tid * 8 + 4096;

  auto stageA = [&](int kt, short* dst) {
    const short* g = A + gA0 + (long)kt * 32;
    gload_lds16(g,                      dst + lo0);
    gload_lds16(g + (long)128 * K_DIM,  dst + lo1);
  };
  auto stageB = [&](int kt, short* dst) {
    const short* g = Bt + gB0 + (long)kt * 32;
    gload_lds16(g,                      dst + lo0);
    gload_lds16(g + (long)128 * K_DIM,  dst + lo1);
  };

  // ---- fragment read offsets (swizzled) ----
  const int fr = lane & 15;
  const int g8 = lane >> 4;     // 16B chunk index 0..3
  int aoff[8], boff[4];
#pragma unroll
  for (int mi = 0; mi < 8; ++mi) {
    int row = wr * 128 + mi * 16 + fr;
    aoff[mi] = row * 32 + ((g8 ^ ((row >> 1) & 3)) << 3);
  }
#pragma unroll
  for (int ni = 0; ni < 4; ++ni) {
    int row = wc * 64 + ni * 16 + fr;
    boff[ni] = row * 32 + ((g8 ^ ((row >> 1) & 3)) << 3);
  }

  f32x4 acc[8][4] = {};

  // ---- prologue: tile0 -> buf0, tile1 -> buf1; drain tile0 only ----
  stageA(0, sA0); stageB(0, sB0);
  stageA(1, sA1); stageB(1, sB1);
  asm volatile("s_waitcnt vmcnt(4)" ::: "memory");
  __builtin_amdgcn_s_barrier();

  short* cA = sA0; short* cB = sB0;   // compute buffer
  short* nA = sA1; short* nB = sB1;   // next (in flight)
  short* pA = sA2; short* pB = sB2;   // prefetch target

  for (int t = 0; t < NKT; ++t) {
    short8 av[4], bv[4];
    // ---- phase 0: mi 0..3, stage A of tile t+2 ----
    if (t < NKT - 2) stageA(t + 2, pA);
#pragma unroll
    for (int i = 0; i < 4; ++i) av[i] = *(const short8*)(cA + aoff[i]);
#pragma unroll
    for (int i = 0; i < 4; ++i) bv[i] = *(const short8*)(cB + boff[i]);
    __builtin_amdgcn_s_barrier();
    __builtin_amdgcn_s_setprio(1);
#pragma unroll
    for (int i = 0; i < 4; ++i)
#pragma unroll
      for (int j = 0; j < 4; ++j)
        acc[i][j] = __builtin_amdgcn_mfma_f32_16x16x32_bf16(av[i], bv[j], acc[i][j], 0, 0, 0);
    __builtin_amdgcn_s_setprio(0);
    __builtin_amdgcn_s_barrier();
    // ---- phase 1: mi 4..7, stage B of tile t+2 ----
    if (t < NKT - 2) stageB(t + 2, pB);
#pragma unroll
    for (int i = 0; i < 4; ++i) av[i] = *(const short8*)(cA + aoff[4 + i]);
    __builtin_amdgcn_s_barrier();
    __builtin_amdgcn_s_setprio(1);
#pragma unroll
    for (int i = 0; i < 4; ++i)
#pragma unroll
      for (int j = 0; j < 4; ++j)
        acc[4 + i][j] = __builtin_amdgcn_mfma_f32_16x16x32_bf16(av[i], bv[j], acc[4 + i][j], 0, 0, 0);
    __builtin_amdgcn_s_setprio(0);
    // ---- boundary: drain tile t+1 (counted; never 0 in steady state) ----
    if (t < NKT - 2) asm volatile("s_waitcnt vmcnt(4)" ::: "memory");
    else             asm volatile("s_waitcnt vmcnt(0)" ::: "memory");
    __builtin_amdgcn_s_barrier();
    // rotate buffers
    short* tAp = cA; cA = nA; nA = pA; pA = tAp;
    short* tBp = cB; cB = nB; nB = pB; pB = tBp;
  }

  // ---- epilogue: C/D layout col=lane&15, row=(lane>>4)*4+j ----
  const int crow = (lane >> 4) * 4;
  const int ccol = lane & 15;
  const long HALF = (long)B_DIM * C_DIM * H_DIM;  // 67108864
  float bia[4]; int cg[4], og[4];
#pragma unroll
  for (int ni = 0; ni < 4; ++ni) {
    int gn = n0 + wc * 64 + ni * 16 + ccol;
    bia[ni] = bias[gn];
    cg[ni] = gn >> 11;
    og[ni] = gn & 2047;
  }
#pragma unroll
  for (int mi = 0; mi < 8; ++mi) {
    int gb0 = m0 + wr * 128 + mi * 16 + crow;
#pragma unroll
    for (int ni = 0; ni < 4; ++ni) {
      int c = cg[ni], o = og[ni];
#pragma unroll
      for (int j = 0; j < 4; ++j) {
        float v = acc[mi][ni][j] + bia[ni];
        long b = gb0 + j;
        if (o < H_DIM) {  // input_gate = sigmoid -> output 1 (second half)
          float r = 1.0f / (1.0f + __expf(-v));
          __builtin_nontemporal_store(r, &out[HALF + (b * C_DIM + c) * H_DIM + o]);
        } else {          // cell_input = tanh -> output 0 (first half)
          float av2 = fabsf(v);
          float e = __expf(-2.0f * av2);
          float r = (1.0f - e) / (1.0f + e);
          r = (v < 0.0f) ? -r : r;
          __builtin_nontemporal_store(r, &out[(b * C_DIM + c) * H_DIM + (o - H_DIM)]);
        }
      }
    }
  }
}

// Correctness-only fallback if workspace is too small for bf16 staging.
__global__ void fallback_kernel(const float* __restrict__ x,
                                const float* __restrict__ h,
                                const float* __restrict__ Wx,
                                const float* __restrict__ bx,
                                const float* __restrict__ Wh,
                                float* __restrict__ out) {
  int b = blockIdx.x;
  int c = blockIdx.y;
  __shared__ float lx[IN_DIM], lh[H_DIM];
  for (int i = threadIdx.x; i < IN_DIM; i += blockDim.x) {
    lx[i] = x[(long)b * IN_DIM + i];
    lh[i] = h[(long)b * H_DIM + i];
  }
  __syncthreads();
  const long HALF = (long)B_DIM * C_DIM * H_DIM;
  for (int o = threadIdx.x; o < 2 * H_DIM; o += blockDim.x) {
    const float* wx = Wx + ((long)c * 2 * H_DIM + o) * IN_DIM;
    const float* wh = Wh + ((long)c * 2 * H_DIM + o) * H_DIM;
    float acc = bx[c * 2 * H_DIM + o];
    for (int k = 0; k < IN_DIM; ++k) acc += lx[k] * wx[k];
    for (int k = 0; k < H_DIM; ++k) acc += lh[k] * wh[k];
    if (o < H_DIM) {
      out[HALF + ((long)b * C_DIM + c) * H_DIM + o] = 1.0f / (1.0f + __expf(-acc));
    } else {
      float av = fabsf(acc);
      float t = __expf(-2.0f * av);
      float r = (1.0f - t) / (1.0f + t);
      out[((long)b * C_DIM + c) * H_DIM + (o - H_DIM)] = (acc < 0.0f) ? -r : r;
    }
  }
}

extern "C" void kernel_launch(void* const* d_in, const int* in_sizes, int n_in,
                              void* d_out, int out_size, void* d_ws, size_t ws_size,
                              hipStream_t stream) {
  const float* x  = (const float*)d_in[0];   // (B, IN)
  const float* h  = (const float*)d_in[1];   // (B, H)
  const float* Wx = (const float*)d_in[2];   // (C, 2H, IN)
  const float* bx = (const float*)d_in[3];   // (C, 2H)
  const float* Wh = (const float*)d_in[4];   // (C, 2H, H)
  float* out = (float*)d_out;                // [cell_input | input_gate], each (B,C,H)

  const size_t needA = (size_t)M_DIM * K_DIM * sizeof(short);  // 16 MiB
  const size_t needB = (size_t)N_DIM * K_DIM * sizeof(short);  // 128 MiB
  if (ws_size < needA + needB) {
    dim3 g(B_DIM, C_DIM);
    fallback_kernel<<<g, 256, 0, stream>>>(x, h, Wx, bx, Wh, out);
    return;
  }

  unsigned short* Abf = (unsigned short*)d_ws;
  unsigned short* Bbf = (unsigned short*)((char*)d_ws + needA);

  convert_pack_kernel<<<2048, 256, 0, stream>>>(x, h, Abf, M_DIM);
  convert_pack_kernel<<<4096, 256, 0, stream>>>(Wx, Wh, Bbf, N_DIM);

  (void)hipFuncSetAttribute((const void*)gemm_act_kernel,
                            hipFuncAttributeMaxDynamicSharedMemorySize, 98304);
  gemm_act_kernel<<<2048, 512, 98304, stream>>>((const short*)Abf, (const short*)Bbf,
                                                bx, out);
}

// Round 3
// 775.143 us; speedup vs baseline: 1.2720x; 1.0666x over previous
//
#include <hip/hip_runtime.h>
#include <hip/hip_bf16.h>

#define IN_DIM 1024
#define H_DIM  1024
#define C_DIM  16
#define B_DIM  4096
#define K_DIM  2048      // IN + H
#define N_DIM  32768     // C * 2H
#define M_DIM  4096      // B
#define NT     32        // K_DIM / 64 K-tiles

typedef __attribute__((ext_vector_type(8))) short short8;
typedef __attribute__((ext_vector_type(4))) float f32x4;

__device__ __forceinline__ unsigned short f2bf_rne(float f) {
  union { float f; unsigned u; } a; a.f = f;
  unsigned r = a.u + 0x7FFFu + ((a.u >> 16) & 1u);
  return (unsigned short)(r >> 16);
}

// Pack rows: out[r][0:1024] = bf16(xs[r][:]), out[r][1024:2048] = bf16(hs[r][:])
__global__ void convert_pack_kernel(const float* __restrict__ xs,
                                    const float* __restrict__ hs,
                                    unsigned short* __restrict__ out,
                                    int rows) {
  long total = (long)rows * (K_DIM / 8);
  for (long i = blockIdx.x * (long)blockDim.x + threadIdx.x; i < total;
       i += (long)gridDim.x * blockDim.x) {
    long e = i * 8;
    int r = (int)(e >> 11);
    int k = (int)(e & 2047);
    const float* src = (k < IN_DIM) ? (xs + (long)r * IN_DIM + k)
                                    : (hs + (long)r * H_DIM + (k - IN_DIM));
    float4 v0 = *(const float4*)(src);
    float4 v1 = *(const float4*)(src + 4);
    union { unsigned short u[8]; short8 s; } p;
    p.u[0] = f2bf_rne(v0.x); p.u[1] = f2bf_rne(v0.y);
    p.u[2] = f2bf_rne(v0.z); p.u[3] = f2bf_rne(v0.w);
    p.u[4] = f2bf_rne(v1.x); p.u[5] = f2bf_rne(v1.y);
    p.u[6] = f2bf_rne(v1.z); p.u[7] = f2bf_rne(v1.w);
    *(short8*)(out + e) = p.s;
  }
}

__device__ __forceinline__ void gload_lds16(const void* g, void* l) {
  __builtin_amdgcn_global_load_lds(
      (const __attribute__((address_space(1))) unsigned int*)g,
      (__attribute__((address_space(3))) unsigned int*)l, 16, 0, 0);
}

// C = A(M x K) * Bt(N x K)^T + bias, fused sigmoid/tanh epilogue.
// 256x256 tile, BK=64, 8 waves (2Mx4N), wave tile 128x64.
// 2 double-buffers (128 KiB), 4 phases/K-tile, 16 MFMA/phase,
// progressive quarter-granular staging, counted vmcnt(6) at iter boundary.
__global__ void __launch_bounds__(512, 2)
gemm_act_kernel(const short* __restrict__ A,   // [M][K] bf16 bits
                const short* __restrict__ Bt,  // [N][K] bf16 bits
                const float* __restrict__ bias,// [N]
                float* __restrict__ out) {
  extern __shared__ short lds[];
  short* sA0 = lds;              // A tile [256][64], 16384 shorts
  short* sA1 = lds + 16384;
  short* sB0 = lds + 32768;      // B tile [256][64]
  short* sB1 = lds + 49152;

  // bijective XCD swizzle (nwg = 2048, divisible by 8); m-fastest tiling
  int cpx = (int)gridDim.x >> 3;
  int wg  = ((int)blockIdx.x & 7) * cpx + ((int)blockIdx.x >> 3);
  int mt = wg & 15;           // M/256 = 16 tiles
  int nt = wg >> 4;           // N/256 = 128 tiles
  int m0 = mt * 256;
  int n0 = nt * 256;

  const int tid  = (int)threadIdx.x;
  const int lane = tid & 63;
  const int wid  = tid >> 6;
  const int wr   = wid >> 2;   // 0..1 -> wave rows wr*128
  const int wc   = wid & 3;    // 0..3 -> wave cols wc*64

  // ---- staging (T2: swizzled global source, linear LDS dest) ----
  // round = 64 rows x 64 cols (8 KB) = 1 load/thread
  const int srow = tid >> 3;                 // 0..63 row within round
  const int sc   = (tid & 7) ^ (srow & 7);   // swizzled src 16B chunk
  const long gAoff = (long)(m0 + srow) * K_DIM + sc * 8;
  const long gBoff = (long)(n0 + srow) * K_DIM + sc * 8;
  const int  dOff  = srow * 64 + (tid & 7) * 8;   // linear LDS dest (shorts)

  auto stageA = [&](int kt, int r0, short* dst) {
    gload_lds16(A + gAoff + (long)r0 * K_DIM + kt * 64, dst + r0 * 64 + dOff);
  };
  auto stageB = [&](int kt, int r0, short* dst) {
    gload_lds16(Bt + gBoff + (long)r0 * K_DIM + kt * 64, dst + r0 * 64 + dOff);
  };

  // ---- fragment LDS offsets (swizzled): row r, chunk kk*4+g8 ----
  const int fr = lane & 15;
  const int g8 = lane >> 4;
  int aoff[8][2], boff[4][2];
#pragma unroll
  for (int mi = 0; mi < 8; ++mi) {
    int r = wr * 128 + mi * 16 + fr;
#pragma unroll
    for (int kk = 0; kk < 2; ++kk)
      aoff[mi][kk] = r * 64 + (((kk * 4 + g8) ^ (r & 7)) << 3);
  }
#pragma unroll
  for (int ni = 0; ni < 4; ++ni) {
    int r = wc * 64 + ni * 16 + fr;
#pragma unroll
    for (int kk = 0; kk < 2; ++kk)
      boff[ni][kk] = r * 64 + (((kk * 4 + g8) ^ (r & 7)) << 3);
  }

  f32x4 acc[8][4] = {};

  // ---- prologue: tile0 complete + tile1 {B, A-low}; leave 6 in flight ----
  stageB(0, 0, sB0); stageB(0, 64, sB0); stageB(0, 128, sB0); stageB(0, 192, sB0);
  stageA(0, 0, sA0); stageA(0, 128, sA0); stageA(0, 64, sA0); stageA(0, 192, sA0);
  stageB(1, 0, sB1); stageB(1, 64, sB1); stageB(1, 128, sB1); stageB(1, 192, sB1);
  stageA(1, 0, sA1); stageA(1, 128, sA1);
  asm volatile("s_waitcnt vmcnt(6)" ::: "memory");
  __builtin_amdgcn_s_barrier();

  // One K-tile: 4 phases. Slot-freedom derivation (race-checked):
  //  - all bv (kk0+kk1) read in ph0 -> B(cur) free after ph0 barrier
  //  - A rows mi0-3 (lower quarters) last read ph1 -> free after ph1 barrier
  //  - A rows mi4-7 (upper quarters) read through ph3 -> staged next iter ph0
  auto iter = [&](int t, short* cA, short* cB, short* nA) {
    const bool s1 = (t + 1) < NT;
    const bool s2 = (t + 2) < NT;
    short8 av0[4], av1[4], bv0[4], bv1[4];
    // ---- ph0: MFMA mi0-3 x kk0; stage A-upper(t+1) -> other buffer ----
    if (s1) { stageA(t + 1, 64, nA); stageA(t + 1, 192, nA); }
#pragma unroll
    for (int i = 0; i < 4; ++i) av0[i] = *(const short8*)(cA + aoff[i][0]);
#pragma unroll
    for (int j = 0; j < 4; ++j) bv0[j] = *(const short8*)(cB + boff[j][0]);
#pragma unroll
    for (int j = 0; j < 4; ++j) bv1[j] = *(const short8*)(cB + boff[j][1]);
    __builtin_amdgcn_s_barrier();
    __builtin_amdgcn_s_setprio(1);
#pragma unroll
    for (int i = 0; i < 4; ++i)
#pragma unroll
      for (int j = 0; j < 4; ++j)
        acc[i][j] = __builtin_amdgcn_mfma_f32_16x16x32_bf16(av0[i], bv0[j], acc[i][j], 0, 0, 0);
    __builtin_amdgcn_s_setprio(0);
    __builtin_amdgcn_s_barrier();
    // ---- ph1: MFMA mi0-3 x kk1; stage Bh0(t+2) into freed B(cur) ----
    if (s2) { stageB(t + 2, 0, cB); stageB(t + 2, 64, cB); }
#pragma unroll
    for (int i = 0; i < 4; ++i) av1[i] = *(const short8*)(cA + aoff[i][1]);
    __builtin_amdgcn_s_barrier();
    __builtin_amdgcn_s_setprio(1);
#pragma unroll
    for (int i = 0; i < 4; ++i)
#pragma unroll
      for (int j = 0; j < 4; ++j)
        acc[i][j] = __builtin_amdgcn_mfma_f32_16x16x32_bf16(av1[i], bv1[j], acc[i][j], 0, 0, 0);
    __builtin_amdgcn_s_setprio(0);
    __builtin_amdgcn_s_barrier();
    // ---- ph2: MFMA mi4-7 x kk0; stage Bh1(t+2) ----
    if (s2) { stageB(t + 2, 128, cB); stageB(t + 2, 192, cB); }
#pragma unroll
    for (int i = 0; i < 4; ++i) av0[i] = *(const short8*)(cA + aoff[4 + i][0]);
    __builtin_amdgcn_s_barrier();
    __builtin_amdgcn_s_setprio(1);
#pragma unroll
    for (int i = 0; i < 4; ++i)
#pragma unroll
      for (int j = 0; j < 4; ++j)
        acc[4 + i][j] = __builtin_amdgcn_mfma_f32_16x16x32_bf16(av0[i], bv0[j], acc[4 + i][j], 0, 0, 0);
    __builtin_amdgcn_s_setprio(0);
    __builtin_amdgcn_s_barrier();
    // ---- ph3: MFMA mi4-7 x kk1; stage A-lower(t+2) (disjoint rows) ----
    if (s2) { stageA(t + 2, 0, cA); stageA(t + 2, 128, cA); }
#pragma unroll
    for (int i = 0; i < 4; ++i) av1[i] = *(const short8*)(cA + aoff[4 + i][1]);
    __builtin_amdgcn_s_barrier();
    __builtin_amdgcn_s_setprio(1);
#pragma unroll
    for (int i = 0; i < 4; ++i)
#pragma unroll
      for (int j = 0; j < 4; ++j)
        acc[4 + i][j] = __builtin_amdgcn_mfma_f32_16x16x32_bf16(av1[i], bv1[j], acc[4 + i][j], 0, 0, 0);
    __builtin_amdgcn_s_setprio(0);
    // counted drain: tile t+1 complete, tile t+2's {B, A-low} stay in flight
    if (s2) asm volatile("s_waitcnt vmcnt(6)" ::: "memory");
    else    asm volatile("s_waitcnt vmcnt(0)" ::: "memory");
    __builtin_amdgcn_s_barrier();
  };

  for (int t = 0; t < NT; t += 2) {
    iter(t,     sA0, sB0, sA1);
    iter(t + 1, sA1, sB1, sA0);
  }

  // ---- epilogue: C/D layout col=lane&15, row=(lane>>4)*4+j ----
  const int crow = (lane >> 4) * 4;
  const int ccol = lane & 15;
  const long HALF = (long)B_DIM * C_DIM * H_DIM;  // 67108864
  float bia[4]; int cg[4], og[4];
#pragma unroll
  for (int ni = 0; ni < 4; ++ni) {
    int gn = n0 + wc * 64 + ni * 16 + ccol;
    bia[ni] = bias[gn];
    cg[ni] = gn >> 11;
    og[ni] = gn & 2047;
  }
#pragma unroll
  for (int mi = 0; mi < 8; ++mi) {
    int gb0 = m0 + wr * 128 + mi * 16 + crow;
#pragma unroll
    for (int ni = 0; ni < 4; ++ni) {
      int c = cg[ni], o = og[ni];
#pragma unroll
      for (int j = 0; j < 4; ++j) {
        float v = acc[mi][ni][j] + bia[ni];
        long b = gb0 + j;
        if (o < H_DIM) {  // input_gate = sigmoid -> output 1 (second half)
          float r = 1.0f / (1.0f + __expf(-v));
          __builtin_nontemporal_store(r, &out[HALF + (b * C_DIM + c) * H_DIM + o]);
        } else {          // cell_input = tanh -> output 0 (first half)
          float av2 = fabsf(v);
          float e = __expf(-2.0f * av2);
          float r = (1.0f - e) / (1.0f + e);
          r = (v < 0.0f) ? -r : r;
          __builtin_nontemporal_store(r, &out[(b * C_DIM + c) * H_DIM + (o - H_DIM)]);
        }
      }
    }
  }
}

// Correctness-only fallback if workspace is too small for bf16 staging.
__global__ void fallback_kernel(const float* __restrict__ x,
                                const float* __restrict__ h,
                                const float* __restrict__ Wx,
                                const float* __restrict__ bx,
                                const float* __restrict__ Wh,
                                float* __restrict__ out) {
  int b = blockIdx.x;
  int c = blockIdx.y;
  __shared__ float lx[IN_DIM], lh[H_DIM];
  for (int i = threadIdx.x; i < IN_DIM; i += blockDim.x) {
    lx[i] = x[(long)b * IN_DIM + i];
    lh[i] = h[(long)b * H_DIM + i];
  }
  __syncthreads();
  const long HALF = (long)B_DIM * C_DIM * H_DIM;
  for (int o = threadIdx.x; o < 2 * H_DIM; o += blockDim.x) {
    const float* wx = Wx + ((long)c * 2 * H_DIM + o) * IN_DIM;
    const float* wh = Wh + ((long)c * 2 * H_DIM + o) * H_DIM;
    float acc = bx[c * 2 * H_DIM + o];
    for (int k = 0; k < IN_DIM; ++k) acc += lx[k] * wx[k];
    for (int k = 0; k < H_DIM; ++k) acc += lh[k] * wh[k];
    if (o < H_DIM) {
      out[HALF + ((long)b * C_DIM + c) * H_DIM + o] = 1.0f / (1.0f + __expf(-acc));
    } else {
      float av = fabsf(acc);
      float t = __expf(-2.0f * av);
      float r = (1.0f - t) / (1.0f + t);
      out[((long)b * C_DIM + c) * H_DIM + (o - H_DIM)] = (acc < 0.0f) ? -r : r;
    }
  }
}

extern "C" void kernel_launch(void* const* d_in, const int* in_sizes, int n_in,
                              void* d_out, int out_size, void* d_ws, size_t ws_size,
                              hipStream_t stream) {
  const float* x  = (const float*)d_in[0];   // (B, IN)
  const float* h  = (const float*)d_in[1];   // (B, H)
  const float* Wx = (const float*)d_in[2];   // (C, 2H, IN)
  const float* bx = (const float*)d_in[3];   // (C, 2H)
  const float* Wh = (const float*)d_in[4];   // (C, 2H, H)
  float* out = (float*)d_out;                // [cell_input | input_gate], each (B,C,H)

  const size_t needA = (size_t)M_DIM * K_DIM * sizeof(short);  // 16 MiB
  const size_t needB = (size_t)N_DIM * K_DIM * sizeof(short);  // 128 MiB
  if (ws_size < needA + needB) {
    dim3 g(B_DIM, C_DIM);
    fallback_kernel<<<g, 256, 0, stream>>>(x, h, Wx, bx, Wh, out);
    return;
  }

  unsigned short* Abf = (unsigned short*)d_ws;
  unsigned short* Bbf = (unsigned short*)((char*)d_ws + needA);

  convert_pack_kernel<<<2048, 256, 0, stream>>>(x, h, Abf, M_DIM);
  convert_pack_kernel<<<4096, 256, 0, stream>>>(Wx, Wh, Bbf, N_DIM);

  (void)hipFuncSetAttribute((const void*)gemm_act_kernel,
                            hipFuncAttributeMaxDynamicSharedMemorySize, 131072);
  gemm_act_kernel<<<2048, 512, 131072, stream>>>((const short*)Abf, (const short*)Bbf,
                                                 bx, out);
}